// Round 10
// baseline (440.663 us; speedup 1.0000x reference)
//
#include <hip/hip_runtime.h>
#include <hip/hip_bf16.h>

#define T_TOTAL 16384
#define D_DIM   2048
#define E_NUM   64
#define BT      64
#define DK      64
#define NKT     (D_DIM / DK)   // 32
#define NB      (T_TOTAL / BT) // 256 blocks = 256 chunks
#define CAP     256

// async global->LDS, 16 B per lane; dest = wave-uniform base + lane*16
#define GLOAD16(g, l)                                                          \
    __builtin_amdgcn_global_load_lds(                                          \
        (const __attribute__((address_space(1))) unsigned int*)(g),            \
        (__attribute__((address_space(3))) unsigned int*)(l), 16, 0, 0)

// ---------------------------------------------------------------------------
// Fused router.  512 threads = 8 waves; block = 64 tokens x 64 experts.
// Lane = token; wave w owns experts e0=8w..8w+7.  x staged in LDS via
// global_load_lds (linear [64][16] float4; every ds_read_b128 is 64 distinct
// rows = full-BW minimum, zero redundancy).  W read via WAVE-UNIFORM scalar
// loads (readfirstlane-forced) -> SGPRs -> FMA SGPR operand: W never touches
// LDS or VGPRs.  Round-9 was LDS-BW-bound (6 redundant b128/kg/wave = 3x the
// FMA time); this structure needs 1 b128/kg/wave (~50% LDS duty).
// Also emits per-block expert histogram for the parallel capacity path.
// ---------------------------------------------------------------------------
__global__ __launch_bounds__(512) void router_fused(
    const float* __restrict__ x, const float* __restrict__ W,
    const float* __restrict__ bias,
    int* __restrict__ top_idx, float* __restrict__ top_prob,
    float* __restrict__ probsum, int* __restrict__ counts,
    unsigned char* __restrict__ hist8)
{
    __shared__ float4 xs4[2][BT][16];   // 32 KB  x[tok][k-quad], linear
    __shared__ float  C[BT][68];        // 17.4 KB logits/probs (padded rows)
    __shared__ int    bh[E_NUM];        // per-block expert histogram

    const int tid = threadIdx.x;
    const int w   = tid >> 6;           // wave 0..7
    const int l   = tid & 63;           // lane = token within tile
    const int lr  = l >> 4;
    const int lc  = l & 15;
    const int t0  = blockIdx.x * BT;
    const float* xb = x + (size_t)t0 * D_DIM;
    const int e0  = __builtin_amdgcn_readfirstlane(w << 3);  // wave expert base

    if (tid < E_NUM) bh[tid] = 0;

    float acc[8] = {0.f,0.f,0.f,0.f,0.f,0.f,0.f,0.f};

    // stage x k-tile kt2 into buffer b: 2 async issues per wave, no VGPRs
    auto stage = [&](int b, int kt2) {
        const int k0 = kt2 * DK;
#pragma unroll
        for (int i = 0; i < 2; ++i) {
            const int r = w * 8 + i * 4;          // lanes cover rows r..r+3
            GLOAD16(xb + (size_t)(r + lr) * D_DIM + k0 + (lc << 2),
                    &xs4[b][r][0]);
        }
    };

    stage(0, 0);
    __syncthreads();                    // vmcnt(0) drained before barrier

    int buf = 0;
    for (int kt = 0; kt < NKT; ++kt) {
        const int kbase = kt * DK;
        if (kt + 1 < NKT) stage(buf ^ 1, kt + 1);   // lands under compute
#pragma unroll
        for (int kg = 0; kg < 16; ++kg) {
            const float4 a = xs4[buf][l][kg];       // 1 full-BW b128 per wave
            const float* wr = W + (size_t)(kbase + (kg << 2)) * E_NUM + e0;
#pragma unroll
            for (int j = 0; j < 8; ++j) {           // uniform -> s_load -> SGPR
                acc[j] = fmaf(a.x, wr[j],
                         fmaf(a.y, wr[E_NUM + j],
                         fmaf(a.z, wr[2 * E_NUM + j],
                         fmaf(a.w, wr[3 * E_NUM + j], acc[j]))));
            }
        }
        __syncthreads();                // stage drained + all reads of buf done
        buf ^= 1;
    }

    // ---- epilogue: bias add, write logits slice (2 x ds_write_b128) ----
    {
        float4 c0, c1;
        c0.x = acc[0] + bias[e0 + 0];  c0.y = acc[1] + bias[e0 + 1];
        c0.z = acc[2] + bias[e0 + 2];  c0.w = acc[3] + bias[e0 + 3];
        c1.x = acc[4] + bias[e0 + 4];  c1.y = acc[5] + bias[e0 + 5];
        c1.z = acc[6] + bias[e0 + 6];  c1.w = acc[7] + bias[e0 + 7];
        *(float4*)&C[l][e0]     = c0;
        *(float4*)&C[l][e0 + 4] = c1;
    }
    __syncthreads();

    // ---- softmax + argmax: 8 lanes per token, experts e = q + 8*e2 ----
    {
        const int t = tid >> 3;         // token 0..63
        const int q = tid & 7;
        float v[8];
        float m = -3.4e38f; int am = 0;
#pragma unroll
        for (int e2 = 0; e2 < 8; ++e2) {
            const float lv = C[t][q + (e2 << 3)];
            v[e2] = lv;
            if (lv > m) { m = lv; am = q + (e2 << 3); }
        }
#pragma unroll
        for (int off = 1; off < 8; off <<= 1) {
            const float om = __shfl_xor(m, off);
            const int   oa = __shfl_xor(am, off);
            if (om > m || (om == m && oa < am)) { m = om; am = oa; }
        }
        float s = 0.f;
#pragma unroll
        for (int e2 = 0; e2 < 8; ++e2) { v[e2] = __expf(v[e2] - m); s += v[e2]; }
#pragma unroll
        for (int off = 1; off < 8; off <<= 1) s += __shfl_xor(s, off);
        const float inv = 1.0f / s;     // prob of the argmax expert
#pragma unroll
        for (int e2 = 0; e2 < 8; ++e2) C[t][q + (e2 << 3)] = v[e2] * inv;
        if (q == 0) {
            top_idx[t0 + t]  = am;
            top_prob[t0 + t] = inv;
            atomicAdd(&counts[am], 1);
            atomicAdd(&bh[am], 1);
        }
    }
    __syncthreads();

    // ---- per-expert prob column sums + histogram out ----
    if (tid < E_NUM) {
        float cs = 0.f;
#pragma unroll
        for (int r = 0; r < BT; ++r) cs += C[r][tid];
        atomicAdd(&probsum[tid], cs);
        hist8[(size_t)blockIdx.x * E_NUM + tid] = (unsigned char)bh[tid];
    }
}

// ---------------------------------------------------------------------------
// Exclusive prefix over 256 chunks for each expert.  Block e, 64 lanes,
// lane owns 4 chunks; wave-scan via shfl_up.
// ---------------------------------------------------------------------------
__global__ __launch_bounds__(64) void scan_kernel(
    const unsigned char* __restrict__ hist8, unsigned short* __restrict__ pfx)
{
    const int e    = blockIdx.x;
    const int lane = threadIdx.x;
    int h[4]; int s = 0;
#pragma unroll
    for (int j = 0; j < 4; ++j) {
        h[j] = hist8[(size_t)(lane * 4 + j) * E_NUM + e];
        s += h[j];
    }
    int incl = s;
#pragma unroll
    for (int off = 1; off < 64; off <<= 1) {
        const int v = __shfl_up(incl, off);
        if (lane >= off) incl += v;
    }
    int run = incl - s;                 // exclusive base for this lane's chunks
#pragma unroll
    for (int j = 0; j < 4; ++j) {
        pfx[(size_t)(lane * 4 + j) * E_NUM + e] = (unsigned short)run;
        run += h[j];
    }
}

// ---------------------------------------------------------------------------
// Apply capacity: block = chunk of 64 tokens, lane = token.  In-chunk rank
// via 6-ballot bit-match on the expert id; global rank = pfx + in-chunk.
// Keep iff inclusive-rank <= CAP  <=>  exclusive base+rank < CAP.
// ---------------------------------------------------------------------------
__global__ __launch_bounds__(64) void apply_kernel(
    const int* __restrict__ top_idx, const float* __restrict__ top_prob,
    const unsigned short* __restrict__ pfx, float* __restrict__ out)
{
    const int c  = blockIdx.x;          // chunk 0..255 (token order)
    const int t  = threadIdx.x;         // lane = token within chunk
    const int gi = c * 64 + t;
    const int idx = top_idx[gi];
    const float p = top_prob[gi];
    unsigned long long mask = ~0ULL;
#pragma unroll
    for (int b = 0; b < 6; ++b) {
        const unsigned long long bb = __ballot((idx >> b) & 1);
        mask &= ((idx >> b) & 1) ? bb : ~bb;
    }
    const int rank = __popcll(mask & ((1ULL << t) - 1ULL));
    const int base = pfx[(size_t)c * E_NUM + idx];
    if (base + rank < CAP) out[(size_t)gi * E_NUM + idx] = p;
}

// ---------------------------------------------------------------------------
// Aux loss: ALPHA * E * sum_e (count_e/T)*(probsum_e/T)
// ---------------------------------------------------------------------------
__global__ __launch_bounds__(64) void aux_kernel(
    const int* __restrict__ counts, const float* __restrict__ probsum,
    float* __restrict__ out)
{
    const int e = threadIdx.x;
    float v = (counts[e] * (1.0f / T_TOTAL)) * (probsum[e] * (1.0f / T_TOTAL));
#pragma unroll
    for (int off = 32; off > 0; off >>= 1) v += __shfl_down(v, off);
    if (e == 0) out[(size_t)T_TOTAL * E_NUM] = 0.01f * 64.0f * v;
}

extern "C" void kernel_launch(void* const* d_in, const int* in_sizes, int n_in,
                              void* d_out, int out_size, void* d_ws, size_t ws_size,
                              hipStream_t stream) {
    const float* x = (const float*)d_in[0];
    const float* W = (const float*)d_in[1];
    const float* b = (const float*)d_in[2];
    float* out = (float*)d_out;
    char*  ws  = (char*)d_ws;

    int*            top_idx  = (int*)ws;                       // 64 KB @ 0
    float*          top_prob = (float*)(ws + 65536);           // 64 KB
    float*          probsum  = (float*)(ws + 131072);          // 256 B
    int*            counts   = (int*)(ws + 131328);            // 256 B
    unsigned char*  hist8    = (unsigned char*)(ws + 131584);  // 16 KB
    unsigned short* pfx      = (unsigned short*)(ws + 147968); // 32 KB

    hipMemsetAsync(d_out, 0, (size_t)(T_TOTAL * E_NUM + 1) * sizeof(float), stream);
    hipMemsetAsync(ws + 131072, 0, 512, stream);

    router_fused<<<NB, 512, 0, stream>>>(x, W, b, top_idx, top_prob,
                                         probsum, counts, hist8);
    scan_kernel<<<E_NUM, 64, 0, stream>>>(hist8, pfx);
    apply_kernel<<<NB, 64, 0, stream>>>(top_idx, top_prob, pfx, out);
    aux_kernel<<<1, 64, 0, stream>>>(counts, probsum, out);
}

// Round 13
// 392.956 us; speedup vs baseline: 1.1214x; 1.1214x over previous
//
#include <hip/hip_runtime.h>
#include <hip/hip_bf16.h>

#define T_TOTAL 16384
#define D_DIM   2048
#define E_NUM   64
#define BT      64
#define DK      64
#define NKT     (D_DIM / DK)   // 32
#define NB      (T_TOTAL / BT) // 256 chunks
#define CAP     256

// async global->LDS, 16 B per lane; dest = wave-uniform base + lane*16
#define GLOAD16(g, l)                                                          \
    __builtin_amdgcn_global_load_lds(                                          \
        (const __attribute__((address_space(1))) unsigned int*)(g),            \
        (__attribute__((address_space(3))) unsigned int*)(l), 16, 0, 0)

// ---------------------------------------------------------------------------
// Fused router.  512 threads = 8 waves; block = 64 tokens x 64 experts.
// Lane = token; wave w owns experts e0=8w..8w+7.  x staged via global_load_lds,
// XOR-SWIZZLED: xs4[r][c] holds x quad (c ^ (r&7))  (round-10 linear layout
// was a 64-lanes-one-bank-quad conflict: 6.3e7 conflict-cycles, +160us).
// Read xs4[l][kg ^ (l&7)]: each 8-lane phase covers all 8 bank quads -> 0
// conflicts.  W via wave-uniform s_load -> SGPR FMA operand (no LDS, no VGPR).
// Emits per-block histogram + per-block probsum partials (no global atomics
// -> no zero-init -> no memsets in kernel_launch).
// ---------------------------------------------------------------------------
__global__ __launch_bounds__(512) void router_fused(
    const float* __restrict__ x, const float* __restrict__ W,
    const float* __restrict__ bias,
    int* __restrict__ top_idx, float* __restrict__ top_prob,
    unsigned char* __restrict__ hist8, float* __restrict__ psum)
{
    __shared__ float4 xs4[2][BT][16];   // 32 KB  x[tok][k-quad], col-swizzled
    __shared__ float  C[BT][68];        // 17.4 KB logits/probs (padded rows)
    __shared__ int    bh[E_NUM];        // per-block expert histogram

    const int tid = threadIdx.x;
    const int w   = tid >> 6;           // wave 0..7
    const int l   = tid & 63;           // lane = token within tile
    const int lr  = l >> 4;
    const int lc  = l & 15;
    const int t0  = blockIdx.x * BT;
    const float* xb = x + (size_t)t0 * D_DIM;
    const int e0  = __builtin_amdgcn_readfirstlane(w << 3);  // wave expert base

    if (tid < E_NUM) bh[tid] = 0;

    float acc[8] = {0.f,0.f,0.f,0.f,0.f,0.f,0.f,0.f};

    // stage x k-tile kt2 into buffer b: source col pre-swizzled so that
    // physical col c of row r holds global quad c ^ (r&7)
    auto stage = [&](int b, int kt2) {
        const int k0 = kt2 * DK;
#pragma unroll
        for (int i = 0; i < 2; ++i) {
            const int r0 = w * 8 + i * 4;         // dest rows r0..r0+3
            const int q  = lc ^ ((r0 + lr) & 7);  // swizzled source quad
            GLOAD16(xb + (size_t)(r0 + lr) * D_DIM + k0 + (q << 2),
                    &xs4[b][r0][0]);
        }
    };

    stage(0, 0);
    __syncthreads();                    // vmcnt(0) drained before barrier

    int buf = 0;
    for (int kt = 0; kt < NKT; ++kt) {
        const int kbase = kt * DK;
        if (kt + 1 < NKT) stage(buf ^ 1, kt + 1);   // lands under compute
#pragma unroll
        for (int kg = 0; kg < 16; ++kg) {
            const float4 a = xs4[buf][l][kg ^ (l & 7)];   // conflict-free
            const float* wr = W + (size_t)(kbase + (kg << 2)) * E_NUM + e0;
#pragma unroll
            for (int j = 0; j < 8; ++j) {           // uniform -> s_load -> SGPR
                acc[j] = fmaf(a.x, wr[j],
                         fmaf(a.y, wr[E_NUM + j],
                         fmaf(a.z, wr[2 * E_NUM + j],
                         fmaf(a.w, wr[3 * E_NUM + j], acc[j]))));
            }
        }
        __syncthreads();                // stage drained + all reads of buf done
        buf ^= 1;
    }

    // ---- epilogue: bias add, write logits slice (2 x ds_write_b128) ----
    {
        float4 c0, c1;
        c0.x = acc[0] + bias[e0 + 0];  c0.y = acc[1] + bias[e0 + 1];
        c0.z = acc[2] + bias[e0 + 2];  c0.w = acc[3] + bias[e0 + 3];
        c1.x = acc[4] + bias[e0 + 4];  c1.y = acc[5] + bias[e0 + 5];
        c1.z = acc[6] + bias[e0 + 6];  c1.w = acc[7] + bias[e0 + 7];
        *(float4*)&C[l][e0]     = c0;
        *(float4*)&C[l][e0 + 4] = c1;
    }
    __syncthreads();

    // ---- softmax + argmax: 8 lanes per token, experts e = q + 8*e2 ----
    {
        const int t = tid >> 3;         // token 0..63
        const int q = tid & 7;
        float v[8];
        float m = -3.4e38f; int am = 0;
#pragma unroll
        for (int e2 = 0; e2 < 8; ++e2) {
            const float lv = C[t][q + (e2 << 3)];
            v[e2] = lv;
            if (lv > m) { m = lv; am = q + (e2 << 3); }
        }
#pragma unroll
        for (int off = 1; off < 8; off <<= 1) {
            const float om = __shfl_xor(m, off);
            const int   oa = __shfl_xor(am, off);
            if (om > m || (om == m && oa < am)) { m = om; am = oa; }
        }
        float s = 0.f;
#pragma unroll
        for (int e2 = 0; e2 < 8; ++e2) { v[e2] = __expf(v[e2] - m); s += v[e2]; }
#pragma unroll
        for (int off = 1; off < 8; off <<= 1) s += __shfl_xor(s, off);
        const float inv = 1.0f / s;     // prob of the argmax expert
#pragma unroll
        for (int e2 = 0; e2 < 8; ++e2) C[t][q + (e2 << 3)] = v[e2] * inv;
        if (q == 0) {
            top_idx[t0 + t]  = am;
            top_prob[t0 + t] = inv;
            atomicAdd(&bh[am], 1);
        }
    }
    __syncthreads();

    // ---- per-block expert prob column sums + histogram out (no atomics) ----
    if (tid < E_NUM) {
        float cs = 0.f;
#pragma unroll
        for (int r = 0; r < BT; ++r) cs += C[r][tid];
        psum[(size_t)blockIdx.x * E_NUM + tid] = cs;
        hist8[(size_t)blockIdx.x * E_NUM + tid] = (unsigned char)bh[tid];
    }
}

// ---------------------------------------------------------------------------
// Per-expert: exclusive prefix over 256 chunks -> pfx; total count -> ecnt;
// probsum reduction -> esum.  Block e, 64 lanes, lane owns 4 chunks.
// ---------------------------------------------------------------------------
__global__ __launch_bounds__(64) void scan_kernel(
    const unsigned char* __restrict__ hist8, const float* __restrict__ psum,
    unsigned short* __restrict__ pfx, int* __restrict__ ecnt,
    float* __restrict__ esum)
{
    const int e    = blockIdx.x;
    const int lane = threadIdx.x;
    int h[4]; int s = 0; float ps = 0.f;
#pragma unroll
    for (int j = 0; j < 4; ++j) {
        const int c = lane * 4 + j;
        h[j] = hist8[(size_t)c * E_NUM + e];
        s += h[j];
        ps += psum[(size_t)c * E_NUM + e];
    }
    int incl = s;
#pragma unroll
    for (int off = 1; off < 64; off <<= 1) {
        const int v = __shfl_up(incl, off);
        if (lane >= off) incl += v;
    }
    int run = incl - s;                 // exclusive base for this lane's chunks
#pragma unroll
    for (int j = 0; j < 4; ++j) {
        pfx[(size_t)(lane * 4 + j) * E_NUM + e] = (unsigned short)run;
        run += h[j];
    }
#pragma unroll
    for (int off = 32; off > 0; off >>= 1) ps += __shfl_down(ps, off);
    if (lane == 63) ecnt[e] = incl;     // total count (inclusive at last lane)
    if (lane == 0)  esum[e] = ps;
}

// ---------------------------------------------------------------------------
// Apply capacity AND write the FULL output row per token (no d_out memset:
// harness poisons d_out with 0xAA before every timed launch, so full
// overwrite is mandatory and also removes the 4.2 MB memsetAsync).
// In-chunk rank via 6-ballot bit-match; keep iff pfx + rank < CAP.
// ---------------------------------------------------------------------------
__global__ __launch_bounds__(64) void apply_kernel(
    const int* __restrict__ top_idx, const float* __restrict__ top_prob,
    const unsigned short* __restrict__ pfx, float* __restrict__ out)
{
    const int c  = blockIdx.x;          // chunk 0..255 (token order)
    const int t  = threadIdx.x;         // lane = token within chunk
    const int gi = c * 64 + t;
    const int idx = top_idx[gi];
    const float p = top_prob[gi];
    unsigned long long mask = ~0ULL;
#pragma unroll
    for (int b = 0; b < 6; ++b) {
        const unsigned long long bb = __ballot((idx >> b) & 1);
        mask &= ((idx >> b) & 1) ? bb : ~bb;
    }
    const int rank = __popcll(mask & ((1ULL << t) - 1ULL));
    const int keep = (pfx[(size_t)c * E_NUM + idx] + rank < CAP) ? 1 : 0;
    const float pv = keep ? p : 0.f;
    float* row = out + (size_t)gi * E_NUM;
#pragma unroll
    for (int j = 0; j < 16; ++j) {      // branch-free row build, static idx
        float4 v;
        v.x = (idx == 4 * j + 0) ? pv : 0.f;
        v.y = (idx == 4 * j + 1) ? pv : 0.f;
        v.z = (idx == 4 * j + 2) ? pv : 0.f;
        v.w = (idx == 4 * j + 3) ? pv : 0.f;
        *(float4*)(row + 4 * j) = v;
    }
}

// ---------------------------------------------------------------------------
// Aux loss: ALPHA * E * sum_e (ecnt_e/T)*(esum_e/T)
// ---------------------------------------------------------------------------
__global__ __launch_bounds__(64) void aux_kernel(
    const int* __restrict__ ecnt, const float* __restrict__ esum,
    float* __restrict__ out)
{
    const int e = threadIdx.x;
    float v = (ecnt[e] * (1.0f / T_TOTAL)) * (esum[e] * (1.0f / T_TOTAL));
#pragma unroll
    for (int off = 32; off > 0; off >>= 1) v += __shfl_down(v, off);
    if (e == 0) out[(size_t)T_TOTAL * E_NUM] = 0.01f * 64.0f * v;
}

extern "C" void kernel_launch(void* const* d_in, const int* in_sizes, int n_in,
                              void* d_out, int out_size, void* d_ws, size_t ws_size,
                              hipStream_t stream) {
    const float* x = (const float*)d_in[0];
    const float* W = (const float*)d_in[1];
    const float* b = (const float*)d_in[2];
    float* out = (float*)d_out;
    char*  ws  = (char*)d_ws;

    int*            top_idx  = (int*)ws;                       // 64 KB @ 0
    float*          top_prob = (float*)(ws + 65536);           // 64 KB
    unsigned char*  hist8    = (unsigned char*)(ws + 131072);  // 16 KB
    float*          psum     = (float*)(ws + 147456);          // 64 KB
    unsigned short* pfx      = (unsigned short*)(ws + 212992); // 32 KB
    int*            ecnt     = (int*)(ws + 245760);            // 256 B
    float*          esum     = (float*)(ws + 246016);          // 256 B

    router_fused<<<NB, 512, 0, stream>>>(x, W, b, top_idx, top_prob,
                                         hist8, psum);
    scan_kernel<<<E_NUM, 64, 0, stream>>>(hist8, psum, pfx, ecnt, esum);
    apply_kernel<<<NB, 64, 0, stream>>>(top_idx, top_prob, pfx, out);
    aux_kernel<<<1, 64, 0, stream>>>(ecnt, esum, out);
}